// Round 4
// baseline (240.070 us; speedup 1.0000x reference)
//
#include <hip/hip_runtime.h>
#include <hip/hip_bf16.h>
#include <stdint.h>

#define BATCH 2048
#define FDIM 512
#define CDIM 64

typedef unsigned short ushort_t;
typedef __attribute__((ext_vector_type(8))) short short8;
typedef __attribute__((ext_vector_type(4))) float f32x4;

__device__ __forceinline__ ushort_t f2bf(float x) {
    union { float f; uint32_t u; } v; v.f = x;
    uint32_t u = v.u;
    uint32_t r = u + 0x7FFFu + ((u >> 16) & 1u);  // round-to-nearest-even
    return (ushort_t)(r >> 16);
}

// ---- fp32 -> bf16 cast (f_feat only; W is consumed fp32 by the GEMM now) ----
__global__ void convert_kernel(const float* __restrict__ src, ushort_t* __restrict__ dst) {
    int idx = blockIdx.x * 256 + threadIdx.x;
    float4 v0 = ((const float4*)src)[idx * 2];
    float4 v1 = ((const float4*)src)[idx * 2 + 1];
    ushort_t p[8] = { f2bf(v0.x), f2bf(v0.y), f2bf(v0.z), f2bf(v0.w),
                      f2bf(v1.x), f2bf(v1.y), f2bf(v1.z), f2bf(v1.w) };
    *(uint4*)&dst[idx * 8] = *(uint4*)p;
}

// ---- fused GEMM (flipped): u[b, n] = sum_j f16[b,j] * W[n,j],  n = c*512 + i
//      W staged fp32 -> LDS (global_load_lds), cvt to bf16 at fragment read.
//      epilogue: part[b,c,iq] = sum_{i in tile} u[b,n] * t_feat[b,i]
#define AS3(p) ((__attribute__((address_space(3))) void*)(p))
#define AS1(p) ((const __attribute__((address_space(1))) void*)(p))

__launch_bounds__(256, 2)
__global__ void gemm_fused_kernel(const ushort_t* __restrict__ f16,
                                  const float* __restrict__ W,
                                  const float* __restrict__ t_feat,
                                  float* __restrict__ part) {
    __shared__ ushort_t As[128 * 32];   // bf16 A tile [row=b][k=j], 64B rows, chunk-swizzled
    __shared__ float    Bs[128 * 32];   // fp32 W tile [perm(n)][k=j], 128B rows, chunk-swizzled
    __shared__ float scratch[256];

    const int tid  = threadIdx.x;
    const int wave = tid >> 6;
    const int lane = tid & 63;
    const int l15  = lane & 15;
    const int lg   = lane >> 4;

    // XCD-aware swizzle: each XCD owns 32 n-tiles; b-tiles iterate innermost.
    const int g   = blockIdx.x + (blockIdx.y << 4);
    const int xcd = g & 7;
    const int s   = g >> 3;
    const int b0  = (s & 15) << 7;
    const int n0  = (xcd * 32 + (s >> 4)) << 7;    // n = c*512 + i

    const int m_base = (wave >> 1) * 64;
    const int nh     = wave & 1;
    const int n_base = nh * 64;

    f32x4 acc[4][4];
    #pragma unroll
    for (int mi = 0; mi < 4; mi++)
        #pragma unroll
        for (int ni = 0; ni < 4; ni++)
            acc[mi][ni] = (f32x4){0.f, 0.f, 0.f, 0.f};

    // --- A staging geometry (bf16, 4 chunks of 16B per row) ---
    // lane tid covers rows p and p+64, chunk cph; content swizzle cg = cph ^ ((p>>1)&3)
    const int pA   = tid >> 2;
    const int cphA = tid & 3;
    const int cgA  = cphA ^ ((pA >> 1) & 3);
    const ushort_t* srcA0 = f16 + (size_t)(b0 + pA) * FDIM + cgA * 8;
    const ushort_t* srcA1 = srcA0 + (size_t)64 * FDIM;

    // --- B staging geometry (fp32, 8 chunks of 16B per row) ---
    // 4 segs/wave; seg covers phys rows seg*8..+7. Phys row p holds global row
    // grow(p) = (p&64)|((p&15)<<2)|((p>>4)&3); phys chunk pc holds global chunk pc^(p&7).
    const float* srcB[4];
    #pragma unroll
    for (int q = 0; q < 4; q++) {
        int seg  = wave * 4 + q;
        int prow = seg * 8 + (lane >> 3);
        int pch  = lane & 7;
        int gch  = pch ^ (prow & 7);
        int grow = (prow & 64) | ((prow & 15) << 2) | ((prow >> 4) & 3);
        srcB[q]  = W + (size_t)(n0 + grow) * FDIM + gch * 4;
    }

    for (int k0 = 0; k0 < FDIM; k0 += 32) {
        __builtin_amdgcn_global_load_lds(AS1(srcA0 + k0), AS3(&As[0 * 2048 + wave * 512]), 16, 0, 0);
        __builtin_amdgcn_global_load_lds(AS1(srcA1 + k0), AS3(&As[1 * 2048 + wave * 512]), 16, 0, 0);
        #pragma unroll
        for (int q = 0; q < 4; q++) {
            int seg = wave * 4 + q;
            __builtin_amdgcn_global_load_lds(AS1(srcB[q] + k0), AS3(&Bs[seg * 256]), 16, 0, 0);
        }
        __syncthreads();

        short8 a[4], b[4];
        #pragma unroll
        for (int mi = 0; mi < 4; mi++) {
            int r = m_base + mi * 16 + l15;
            a[mi] = *(const short8*)&As[r * 32 + (lg ^ ((r >> 1) & 3)) * 8];
        }
        #pragma unroll
        for (int ni = 0; ni < 4; ni++) {
            int q2 = n_base + ni * 16 + l15;
            int h  = q2 & 7;
            float4 v0 = *(const float4*)&Bs[q2 * 32 + (((2 * lg) ^ h) * 4)];
            float4 v1 = *(const float4*)&Bs[q2 * 32 + (((2 * lg + 1) ^ h) * 4)];
            union { __hip_bfloat162 h2[4]; short8 s; } pk;
            pk.h2[0] = __float22bfloat162_rn(make_float2(v0.x, v0.y));
            pk.h2[1] = __float22bfloat162_rn(make_float2(v0.z, v0.w));
            pk.h2[2] = __float22bfloat162_rn(make_float2(v1.x, v1.y));
            pk.h2[3] = __float22bfloat162_rn(make_float2(v1.z, v1.w));
            b[ni] = pk.s;
        }

        #pragma unroll
        for (int mi = 0; mi < 4; mi++)
            #pragma unroll
            for (int ni = 0; ni < 4; ni++)
                acc[mi][ni] = __builtin_amdgcn_mfma_f32_16x16x32_bf16(a[mi], b[ni], acc[mi][ni], 0, 0, 0);

        __syncthreads();
    }

    // Epilogue. D col l15 of frag ni holds global n = n0 + n_base + l15*4 + ni
    // (4 consecutive i per lane). D row = lg*4 + reg -> b.
    const int c  = n0 >> 9;
    const int iq = (n0 >> 7) & 3;
    const int i_base = (n0 & 511) + n_base + l15 * 4;

    #pragma unroll
    for (int mi = 0; mi < 4; mi++) {
        #pragma unroll
        for (int r = 0; r < 4; r++) {
            int b_idx = b0 + m_base + mi * 16 + lg * 4 + r;
            const float4 tv = *(const float4*)&t_feat[(size_t)b_idx * FDIM + i_base];
            float sv = acc[mi][0][r] * tv.x + acc[mi][1][r] * tv.y
                     + acc[mi][2][r] * tv.z + acc[mi][3][r] * tv.w;
            sv += __shfl_xor(sv, 1, 64);
            sv += __shfl_xor(sv, 2, 64);
            sv += __shfl_xor(sv, 4, 64);
            sv += __shfl_xor(sv, 8, 64);
            if (l15 == 0)
                scratch[(m_base + mi * 16 + lg * 4 + r) * 2 + nh] = sv;
        }
    }
    __syncthreads();
    if (tid < 128) {
        float v = scratch[tid * 2] + scratch[tid * 2 + 1];
        part[(((size_t)(b0 + tid)) * 64 + c) * 4 + iq] = v;
    }
}

// ---- MLP head: 32 threads per batch row, shuffle-reduced ----
__global__ void mlp_kernel(const float* __restrict__ part,
                           const float* __restrict__ b_proj,
                           const float* __restrict__ W1, const float* __restrict__ b1,
                           const float* __restrict__ W2, const float* __restrict__ b2,
                           float* __restrict__ out) {
    __shared__ float h[8][64];
    const int tid = threadIdx.x;
    const int bl  = tid >> 5;        // 0..7
    const int o   = tid & 31;
    const int b   = blockIdx.x * 8 + bl;

    #pragma unroll
    for (int c = o; c < 64; c += 32) {
        float4 v = *(const float4*)&part[(((size_t)b * 64 + c)) * 4];
        float sv = v.x + v.y + v.z + v.w + b_proj[c];
        h[bl][c] = sv > 0.f ? sv : 0.f;
    }
    __syncthreads();

    float sv = b1[o];
    #pragma unroll
    for (int c = 0; c < 64; c++) sv += h[bl][c] * W1[o * 64 + c];
    float v = (sv > 0.f ? sv : 0.f) * W2[o];
    v += __shfl_xor(v, 1, 32);
    v += __shfl_xor(v, 2, 32);
    v += __shfl_xor(v, 4, 32);
    v += __shfl_xor(v, 8, 32);
    v += __shfl_xor(v, 16, 32);
    if (o == 0) out[b] = v + b2[0];
}

extern "C" void kernel_launch(void* const* d_in, const int* in_sizes, int n_in,
                              void* d_out, int out_size, void* d_ws, size_t ws_size,
                              hipStream_t stream) {
    const float* t_feat = (const float*)d_in[0];
    const float* f_feat = (const float*)d_in[1];
    const float* W_proj = (const float*)d_in[2];
    const float* b_proj = (const float*)d_in[3];
    const float* W1     = (const float*)d_in[4];
    const float* b1     = (const float*)d_in[5];
    const float* W2     = (const float*)d_in[6];
    const float* b2     = (const float*)d_in[7];
    float* out = (float*)d_out;

    uint8_t* ws = (uint8_t*)d_ws;
    ushort_t* f16  = (ushort_t*)(ws);                 // 2 MiB
    float*    part = (float*)(ws + 2097152);          // 2 MiB

    convert_kernel<<<dim3((BATCH * FDIM) / 2048), dim3(256), 0, stream>>>(f_feat, f16);

    gemm_fused_kernel<<<dim3(BATCH / 128, (CDIM * FDIM) / 128), dim3(256), 0, stream>>>(
        f16, W_proj, t_feat, part);

    mlp_kernel<<<dim3(BATCH / 8), dim3(256), 0, stream>>>(part, b_proj, W1, b1, W2, b2, out);
}

// Round 5
// 213.915 us; speedup vs baseline: 1.1223x; 1.1223x over previous
//
#include <hip/hip_runtime.h>
#include <hip/hip_bf16.h>
#include <stdint.h>

#define BATCH 2048
#define FDIM 512
#define CDIM 64

typedef unsigned short ushort_t;
typedef __attribute__((ext_vector_type(8))) short short8;
typedef __attribute__((ext_vector_type(4))) float f32x4;

__device__ __forceinline__ ushort_t f2bf(float x) {
    union { float f; uint32_t u; } v; v.f = x;
    uint32_t u = v.u;
    uint32_t r = u + 0x7FFFu + ((u >> 16) & 1u);  // round-to-nearest-even
    return (ushort_t)(r >> 16);
}
__device__ __forceinline__ float bf2f(ushort_t u) {
    union { float f; uint32_t v; } x; x.v = ((uint32_t)u) << 16; return x.f;
}

// ---- fp32 -> bf16 cast, 8 elems / thread, 16B stores (W_proj) ----
__global__ void convert_kernel(const float* __restrict__ src, ushort_t* __restrict__ dst) {
    int idx = blockIdx.x * 256 + threadIdx.x;
    float4 v0 = ((const float4*)src)[idx * 2];
    float4 v1 = ((const float4*)src)[idx * 2 + 1];
    ushort_t p[8] = { f2bf(v0.x), f2bf(v0.y), f2bf(v0.z), f2bf(v0.w),
                      f2bf(v1.x), f2bf(v1.y), f2bf(v1.z), f2bf(v1.w) };
    *(uint4*)&dst[idx * 8] = *(uint4*)p;
}

// ---- fused convert for f_feat and t_feat (1M elems each) ----
__global__ void convert_ft_kernel(const float* __restrict__ f, ushort_t* __restrict__ f16,
                                  const float* __restrict__ t, ushort_t* __restrict__ t16) {
    int blk = blockIdx.x;
    const float* src = (blk < 512) ? f : t;
    ushort_t* dst    = (blk < 512) ? f16 : t16;
    int idx = (blk & 511) * 256 + threadIdx.x;
    float4 v0 = ((const float4*)src)[idx * 2];
    float4 v1 = ((const float4*)src)[idx * 2 + 1];
    ushort_t p[8] = { f2bf(v0.x), f2bf(v0.y), f2bf(v0.z), f2bf(v0.w),
                      f2bf(v1.x), f2bf(v1.y), f2bf(v1.z), f2bf(v1.w) };
    *(uint4*)&dst[idx * 8] = *(uint4*)p;
}

// ---- fused GEMM (flipped, R2-proven structure): u[b,n] = sum_j f16[b,j]*Wb[n,j]
//      n = c*512 + i;  epilogue: part[b,c,iq] = sum_i u[b,n] * t16[b,i]
#define AS3(p) ((__attribute__((address_space(3))) void*)(p))
#define AS1(p) ((const __attribute__((address_space(1))) void*)(p))

__launch_bounds__(256, 2)
__global__ void gemm_fused_kernel(const ushort_t* __restrict__ f16,
                                  const ushort_t* __restrict__ Wb,
                                  const ushort_t* __restrict__ t16,
                                  float* __restrict__ part) {
    __shared__ ushort_t As[128 * 32];   // [row=b][k=j] 64B rows, chunk-swizzled
    __shared__ ushort_t Bs[128 * 32];   // row-permuted + chunk-swizzled
    __shared__ float scratch[256];

    const int tid  = threadIdx.x;
    const int wave = tid >> 6;
    const int lane = tid & 63;
    const int l15  = lane & 15;
    const int lg   = lane >> 4;

    const int b0 = blockIdx.x * 128;
    const int n0 = blockIdx.y * 128;    // n = c*512 + i

    const int m_base = (wave >> 1) * 64;
    const int nh     = wave & 1;
    const int n_base = nh * 64;

    f32x4 acc[4][4];
    #pragma unroll
    for (int mi = 0; mi < 4; mi++)
        #pragma unroll
        for (int ni = 0; ni < 4; ni++)
            acc[mi][ni] = (f32x4){0.f, 0.f, 0.f, 0.f};

    // staging: lane tid -> phys (row p, chunk cph); content: global chunk cg = cph ^ ((p>>1)&3)
    // B row-permute: phys row p holds global n_local = ((p&15)<<2) | (p>>4)
    const int p    = tid >> 2;
    const int cph  = tid & 3;
    const int cg   = cph ^ ((p >> 1) & 3);
    const int nrot = ((p & 15) << 2) | (p >> 4);

    const ushort_t* gA0 = f16 + (size_t)(b0 + p) * FDIM + cg * 8;
    const ushort_t* gA1 = f16 + (size_t)(b0 + 64 + p) * FDIM + cg * 8;
    const ushort_t* gB0 = Wb + (size_t)(n0 + nrot) * FDIM + cg * 8;
    const ushort_t* gB1 = Wb + (size_t)(n0 + 64 + nrot) * FDIM + cg * 8;

    for (int k0 = 0; k0 < FDIM; k0 += 32) {
        __builtin_amdgcn_global_load_lds(AS1(gA0 + k0), AS3(&As[0 * 2048 + wave * 512]), 16, 0, 0);
        __builtin_amdgcn_global_load_lds(AS1(gA1 + k0), AS3(&As[1 * 2048 + wave * 512]), 16, 0, 0);
        __builtin_amdgcn_global_load_lds(AS1(gB0 + k0), AS3(&Bs[0 * 2048 + wave * 512]), 16, 0, 0);
        __builtin_amdgcn_global_load_lds(AS1(gB1 + k0), AS3(&Bs[1 * 2048 + wave * 512]), 16, 0, 0);
        __syncthreads();

        short8 a[4], b[4];
        #pragma unroll
        for (int mi = 0; mi < 4; mi++) {
            int r = m_base + mi * 16 + l15;
            a[mi] = *(const short8*)&As[r * 32 + (lg ^ ((r >> 1) & 3)) * 8];
        }
        #pragma unroll
        for (int ni = 0; ni < 4; ni++) {
            int q = n_base + ni * 16 + l15;
            b[ni] = *(const short8*)&Bs[q * 32 + (lg ^ ((q >> 1) & 3)) * 8];
        }

        #pragma unroll
        for (int mi = 0; mi < 4; mi++)
            #pragma unroll
            for (int ni = 0; ni < 4; ni++)
                acc[mi][ni] = __builtin_amdgcn_mfma_f32_16x16x32_bf16(a[mi], b[ni], acc[mi][ni], 0, 0, 0);

        __syncthreads();
    }

    // Epilogue. D col l15 of frag ni holds global n = n0 + n_base + l15*4 + ni
    // (4 consecutive i per lane). D row = lg*4 + reg -> b. t read as bf16x4 (8B).
    const int c  = n0 >> 9;
    const int iq = (n0 >> 7) & 3;
    const int i_base = (n0 & 511) + n_base + l15 * 4;

    #pragma unroll
    for (int mi = 0; mi < 4; mi++) {
        #pragma unroll
        for (int r = 0; r < 4; r++) {
            int b_idx = b0 + m_base + mi * 16 + lg * 4 + r;
            ushort4 tv = *(const ushort4*)&t16[(size_t)b_idx * FDIM + i_base];
            float sv = acc[mi][0][r] * bf2f(tv.x) + acc[mi][1][r] * bf2f(tv.y)
                     + acc[mi][2][r] * bf2f(tv.z) + acc[mi][3][r] * bf2f(tv.w);
            sv += __shfl_xor(sv, 1, 64);
            sv += __shfl_xor(sv, 2, 64);
            sv += __shfl_xor(sv, 4, 64);
            sv += __shfl_xor(sv, 8, 64);
            if (l15 == 0)
                scratch[(m_base + mi * 16 + lg * 4 + r) * 2 + nh] = sv;
        }
    }
    __syncthreads();
    if (tid < 128) {
        float v = scratch[tid * 2] + scratch[tid * 2 + 1];
        part[(((size_t)(b0 + tid)) * 64 + c) * 4 + iq] = v;
    }
}

// ---- MLP head: 32 threads per batch row, shuffle-reduced ----
__global__ void mlp_kernel(const float* __restrict__ part,
                           const float* __restrict__ b_proj,
                           const float* __restrict__ W1, const float* __restrict__ b1,
                           const float* __restrict__ W2, const float* __restrict__ b2,
                           float* __restrict__ out) {
    __shared__ float h[8][64];
    const int tid = threadIdx.x;
    const int bl  = tid >> 5;        // 0..7
    const int o   = tid & 31;
    const int b   = blockIdx.x * 8 + bl;

    #pragma unroll
    for (int c = o; c < 64; c += 32) {
        float4 v = *(const float4*)&part[(((size_t)b * 64 + c)) * 4];
        float sv = v.x + v.y + v.z + v.w + b_proj[c];
        h[bl][c] = sv > 0.f ? sv : 0.f;
    }
    __syncthreads();

    float sv = b1[o];
    #pragma unroll
    for (int c = 0; c < 64; c++) sv += h[bl][c] * W1[o * 64 + c];
    float v = (sv > 0.f ? sv : 0.f) * W2[o];
    v += __shfl_xor(v, 1, 32);
    v += __shfl_xor(v, 2, 32);
    v += __shfl_xor(v, 4, 32);
    v += __shfl_xor(v, 8, 32);
    v += __shfl_xor(v, 16, 32);
    if (o == 0) out[b] = v + b2[0];
}

extern "C" void kernel_launch(void* const* d_in, const int* in_sizes, int n_in,
                              void* d_out, int out_size, void* d_ws, size_t ws_size,
                              hipStream_t stream) {
    const float* t_feat = (const float*)d_in[0];
    const float* f_feat = (const float*)d_in[1];
    const float* W_proj = (const float*)d_in[2];
    const float* b_proj = (const float*)d_in[3];
    const float* W1     = (const float*)d_in[4];
    const float* b1     = (const float*)d_in[5];
    const float* W2     = (const float*)d_in[6];
    const float* b2     = (const float*)d_in[7];
    float* out = (float*)d_out;

    uint8_t* ws = (uint8_t*)d_ws;
    ushort_t* Wb   = (ushort_t*)(ws);                          // 32 MiB
    ushort_t* f16  = (ushort_t*)(ws + 33554432);               // 2 MiB
    ushort_t* t16  = (ushort_t*)(ws + 33554432 + 2097152);     // 2 MiB
    float*    part = (float*)(ws + 33554432 + 2 * 2097152);    // 2 MiB

    convert_kernel<<<dim3((CDIM * FDIM * FDIM) / 2048), dim3(256), 0, stream>>>(W_proj, Wb);
    convert_ft_kernel<<<dim3(1024), dim3(256), 0, stream>>>(f_feat, f16, t_feat, t16);

    gemm_fused_kernel<<<dim3(BATCH / 128, (CDIM * FDIM) / 128), dim3(256), 0, stream>>>(
        f16, Wb, t16, part);

    mlp_kernel<<<dim3(BATCH / 8), dim3(256), 0, stream>>>(part, b_proj, W1, b1, W2, b2, out);
}